// Round 1
// baseline (1006.107 us; speedup 1.0000x reference)
//
#include <hip/hip_runtime.h>
#include <hip/hip_bf16.h>

// GraphUpsampler: N=4096 -> M=8192 dense GCN, 3 iterations, out = sigmoid(Xu@Xu.T) f32 [8192,8192].
// Strategy: bf16 storage + MFMA 16x16x32, f32 accum. Adj materialized bf16 (134MB) with fused
// column-sum (deg) in its producer. A_out for iters 0,1 is dead code -> skipped.

#define N_NODES 4096
#define M_NODES 8192
#define DIM 128
#define SPLITS 8

typedef __attribute__((ext_vector_type(4))) float f32x4;
typedef __attribute__((ext_vector_type(8))) short bf16x8;

__device__ __forceinline__ unsigned short f2bf(float f) {
  union { float f; unsigned u; } v; v.f = f;
  unsigned r = v.u + 0x7fffu + ((v.u >> 16) & 1u);   // round-to-nearest-even
  return (unsigned short)(r >> 16);
}

__device__ __forceinline__ void gld16(unsigned short* lds, const unsigned short* g) {
  __builtin_amdgcn_global_load_lds(
      (const __attribute__((address_space(1))) unsigned int*)g,
      (__attribute__((address_space(3))) unsigned int*)lds, 16, 0, 0);
}

__device__ __forceinline__ float sigmoidf_(float x) { return 1.0f / (1.0f + __expf(-x)); }

// ---------------- small cast / init kernels ----------------

__global__ void cast_x_kernel(const float* __restrict__ X, unsigned short* __restrict__ Xu,
                              unsigned short* __restrict__ XT) {
  int idx = blockIdx.x * 256 + threadIdx.x;          // over N*DIM
  int i = idx >> 7, c = idx & 127;
  unsigned short b = f2bf(X[idx]);
  Xu[idx] = b;
  XT[(size_t)c * N_NODES + i] = b;                   // X^T [128][4096]
}

__global__ void cast_wup_kernel(const float4* __restrict__ W, ushort4* __restrict__ Wb) {
  int idx = blockIdx.x * 256 + threadIdx.x;          // over N*N/4
  float4 v = W[idx];
  ushort4 o;
  o.x = f2bf(v.x); o.y = f2bf(v.y); o.z = f2bf(v.z); o.w = f2bf(v.w);
  Wb[idx] = o;
}

__global__ void cast_wt_kernel(const float* __restrict__ W, unsigned short* __restrict__ WT) {
  int idx = blockIdx.x * 256 + threadIdx.x;          // 128*128
  int k = idx >> 7, c = idx & 127;
  WT[c * DIM + k] = f2bf(W[idx]);                    // W^T [out c][in k]
}

// Fill 3 A-blocks of Adj (A is symmetric by construction -> A.T == A) + colsum(A)
__global__ void cast_a_kernel(const float* __restrict__ A, unsigned short* __restrict__ Adj,
                              float* __restrict__ colsumA) {
  int c = blockIdx.x * 256 + threadIdx.x;
  int r0 = blockIdx.y * 128;
  float s = 0.f;
  for (int r = 0; r < 128; ++r) {
    int row = r0 + r;
    float a = A[(size_t)row * N_NODES + c];
    unsigned short b = f2bf(a);
    Adj[(size_t)row * M_NODES + c] = b;                       // top-left
    Adj[(size_t)(row + N_NODES) * M_NODES + c] = b;           // bottom-left
    Adj[(size_t)row * M_NODES + N_NODES + c] = b;             // top-right (= A.T by symmetry)
    s += a;
  }
  atomicAdd(&colsumA[c], s);
}

__global__ void init_deg_kernel(const float* __restrict__ colsumA, float* __restrict__ deg) {
  int i = blockIdx.x * 256 + threadIdx.x;            // 8192
  deg[i] = (i < N_NODES) ? 2.0f * colsumA[i] : colsumA[i - N_NODES];
}

__global__ void dinv_kernel(const float* __restrict__ deg, float* __restrict__ dinv) {
  int i = blockIdx.x * 256 + threadIdx.x;
  float d = deg[i];
  dinv[i] = d > 0.f ? rsqrtf(d) : 0.f;
}

// ---------------- split-K GEMM: C_partial[split] = A[M,K]bf16 @ B (given as BT[128,K]) ----------------

__global__ __launch_bounds__(256)
void gemm_split_kernel(const unsigned short* __restrict__ A, long lda,
                       const unsigned short* __restrict__ BT, long ldb,
                       float* __restrict__ accOut, int M, int kChunk) {
  __shared__ __align__(16) unsigned short lA[128 * 32];
  __shared__ __align__(16) unsigned short lB[128 * 32];
  const int t = threadIdx.x;
  const int w = t >> 6, lane = t & 63;
  const int q = lane >> 4, l15 = lane & 15;
  const int m0 = blockIdx.x * 128;
  const long k0b = (long)blockIdx.y * kChunk;
  const int arow = t >> 2, achk = t & 3;

  f32x4 acc[2][8];
#pragma unroll
  for (int a = 0; a < 2; ++a)
#pragma unroll
    for (int b = 0; b < 8; ++b) acc[a][b] = (f32x4)0.f;

  for (int ks = 0; ks < kChunk; ks += 32) {
    const long k0 = k0b + ks;
    __syncthreads();   // previous compute done before LDS overwrite
    gld16(&lA[(size_t)t * 8], &A[(size_t)(m0 + arow) * lda + k0 + achk * 8]);
    gld16(&lA[2048 + (size_t)t * 8], &A[(size_t)(m0 + 64 + arow) * lda + k0 + achk * 8]);
    gld16(&lB[(size_t)t * 8], &BT[(size_t)arow * ldb + k0 + achk * 8]);
    gld16(&lB[2048 + (size_t)t * 8], &BT[(size_t)(64 + arow) * ldb + k0 + achk * 8]);
    __syncthreads();   // waits vmcnt(0) -> LDS valid
    bf16x8 a0 = *(const bf16x8*)&lA[(w * 32 + l15) * 32 + q * 8];
    bf16x8 a1 = *(const bf16x8*)&lA[(w * 32 + 16 + l15) * 32 + q * 8];
#pragma unroll
    for (int nt = 0; nt < 8; ++nt) {
      bf16x8 b = *(const bf16x8*)&lB[(nt * 16 + l15) * 32 + q * 8];
      acc[0][nt] = __builtin_amdgcn_mfma_f32_16x16x32_bf16(a0, b, acc[0][nt], 0, 0, 0);
      acc[1][nt] = __builtin_amdgcn_mfma_f32_16x16x32_bf16(a1, b, acc[1][nt], 0, 0, 0);
    }
  }
  float* slice = accOut + (size_t)blockIdx.y * M * DIM;
#pragma unroll
  for (int mt = 0; mt < 2; ++mt)
#pragma unroll
    for (int nt = 0; nt < 8; ++nt)
#pragma unroll
      for (int i = 0; i < 4; ++i) {
        int row = m0 + w * 32 + mt * 16 + q * 4 + i;
        slice[(size_t)row * DIM + nt * 16 + l15] = acc[mt][nt][i];
      }
}

// sum split partials + epilogue -> bf16 Xu
// mode 0: v = s + bias_row[row]            (W_up result)
// mode 1: v = relu(dinv[row]*s + bias_col[c])   (GCN result)
__global__ void reduce_acc_kernel(const float* __restrict__ acc, int M,
                                  unsigned short* __restrict__ dst,
                                  const float* __restrict__ bias_row,
                                  const float* __restrict__ bias_col,
                                  const float* __restrict__ dinv, int mode) {
  int idx = blockIdx.x * 256 + threadIdx.x;          // M*DIM
  float s = 0.f;
#pragma unroll
  for (int sp = 0; sp < SPLITS; ++sp) s += acc[(size_t)sp * M * DIM + idx];
  int row = idx >> 7, c = idx & 127;
  float v;
  if (mode == 0) v = s + bias_row[row];
  else { v = dinv[row] * s + bias_col[c]; v = fmaxf(v, 0.f); }
  dst[idx] = f2bf(v);
}

// ---------------- rebuild: out = sigmoid(XA @ XB^T), K=128 ----------------
// MODE 0: bf16 out + fused column sums into deg.  MODE 1: f32 out (final).

template <int MODE>
__global__ __launch_bounds__(256)
void rebuild_kernel(const unsigned short* __restrict__ XA,
                    const unsigned short* __restrict__ XB,
                    void* __restrict__ out, long ldo, float* __restrict__ deg) {
  __shared__ __align__(16) unsigned short smem[32768];   // lA[4][128][32] + lB[4][128][32]
  __shared__ float lcol[128];
  unsigned short* lA = smem;
  unsigned short* lB = smem + 16384;
  const int t = threadIdx.x, w = t >> 6, lane = t & 63;
  const int q = lane >> 4, l15 = lane & 15;
  const int i0 = blockIdx.x * 128, j0 = blockIdx.y * 128;
  const int srow = t >> 2, schk = t & 3;
#pragma unroll
  for (int kk = 0; kk < 4; ++kk)
#pragma unroll
    for (int h = 0; h < 2; ++h) {
      gld16(&lA[kk * 4096 + h * 2048 + t * 8],
            &XA[(size_t)(i0 + h * 64 + srow) * DIM + kk * 32 + schk * 8]);
      gld16(&lB[kk * 4096 + h * 2048 + t * 8],
            &XB[(size_t)(j0 + h * 64 + srow) * DIM + kk * 32 + schk * 8]);
    }
  if (MODE == 0 && t < 128) lcol[t] = 0.f;
  __syncthreads();

  f32x4 acc[2][8];
#pragma unroll
  for (int a = 0; a < 2; ++a)
#pragma unroll
    for (int b = 0; b < 8; ++b) acc[a][b] = (f32x4)0.f;

#pragma unroll
  for (int kk = 0; kk < 4; ++kk) {
    bf16x8 a0 = *(const bf16x8*)&lA[kk * 4096 + (w * 32 + l15) * 32 + q * 8];
    bf16x8 a1 = *(const bf16x8*)&lA[kk * 4096 + (w * 32 + 16 + l15) * 32 + q * 8];
#pragma unroll
    for (int nt = 0; nt < 8; ++nt) {
      bf16x8 b = *(const bf16x8*)&lB[kk * 4096 + (nt * 16 + l15) * 32 + q * 8];
      acc[0][nt] = __builtin_amdgcn_mfma_f32_16x16x32_bf16(a0, b, acc[0][nt], 0, 0, 0);
      acc[1][nt] = __builtin_amdgcn_mfma_f32_16x16x32_bf16(a1, b, acc[1][nt], 0, 0, 0);
    }
  }
  __syncthreads();   // staging reads done; smem reusable as C-tile

  if (MODE == 0) {
    unsigned short* lC = smem;   // [128][136] bf16, padded for bank spread, 16B-aligned rows
#pragma unroll
    for (int mt = 0; mt < 2; ++mt)
#pragma unroll
      for (int nt = 0; nt < 8; ++nt) {
        float cs = 0.f;
#pragma unroll
        for (int i = 0; i < 4; ++i) {
          float sv = sigmoidf_(acc[mt][nt][i]);
          cs += sv;
          lC[(w * 32 + mt * 16 + q * 4 + i) * 136 + nt * 16 + l15] = f2bf(sv);
        }
        cs += __shfl_xor(cs, 16);
        cs += __shfl_xor(cs, 32);
        if (lane < 16) atomicAdd(&lcol[nt * 16 + lane], cs);
      }
    __syncthreads();
    unsigned short* og = (unsigned short*)out;
#pragma unroll
    for (int cc = 0; cc < 8; ++cc) {
      int ch = t + cc * 256;                     // 0..2047
      int row = ch >> 4, c16 = ch & 15;
      *(bf16x8*)&og[(size_t)(i0 + row) * ldo + j0 + c16 * 8] =
          *(const bf16x8*)&lC[row * 136 + c16 * 8];
    }
    if (t < 128) atomicAdd(&deg[j0 + t], lcol[t]);
  } else {
    float* og = (float*)out;
#pragma unroll
    for (int mt = 0; mt < 2; ++mt)
#pragma unroll
      for (int nt = 0; nt < 8; ++nt)
#pragma unroll
        for (int i = 0; i < 4; ++i)
          og[(size_t)(i0 + w * 32 + mt * 16 + q * 4 + i) * ldo + j0 + nt * 16 + l15] =
              sigmoidf_(acc[mt][nt][i]);
  }
}

// ---------------- Z^T = (dinv ⊙ (Xu @ W)) transposed, [128][8192] ----------------

__global__ __launch_bounds__(256)
void yz_kernel(const unsigned short* __restrict__ Xu, const unsigned short* __restrict__ WT,
               const float* __restrict__ dinv, unsigned short* __restrict__ ZT, int ldz) {
  __shared__ __align__(16) unsigned short smem[32768];
  unsigned short* lA = smem;
  unsigned short* lB = smem + 16384;
  const int t = threadIdx.x, w = t >> 6, lane = t & 63;
  const int q = lane >> 4, l15 = lane & 15;
  const int r0 = blockIdx.x * 128;
  const int srow = t >> 2, schk = t & 3;
#pragma unroll
  for (int kk = 0; kk < 4; ++kk)
#pragma unroll
    for (int h = 0; h < 2; ++h) {
      gld16(&lA[kk * 4096 + h * 2048 + t * 8],
            &Xu[(size_t)(r0 + h * 64 + srow) * DIM + kk * 32 + schk * 8]);
      gld16(&lB[kk * 4096 + h * 2048 + t * 8],
            &WT[(size_t)(h * 64 + srow) * DIM + kk * 32 + schk * 8]);
    }
  __syncthreads();

  f32x4 acc[2][8];
#pragma unroll
  for (int a = 0; a < 2; ++a)
#pragma unroll
    for (int b = 0; b < 8; ++b) acc[a][b] = (f32x4)0.f;

#pragma unroll
  for (int kk = 0; kk < 4; ++kk) {
    bf16x8 a0 = *(const bf16x8*)&lA[kk * 4096 + (w * 32 + l15) * 32 + q * 8];
    bf16x8 a1 = *(const bf16x8*)&lA[kk * 4096 + (w * 32 + 16 + l15) * 32 + q * 8];
#pragma unroll
    for (int nt = 0; nt < 8; ++nt) {
      bf16x8 b = *(const bf16x8*)&lB[kk * 4096 + (nt * 16 + l15) * 32 + q * 8];
      acc[0][nt] = __builtin_amdgcn_mfma_f32_16x16x32_bf16(a0, b, acc[0][nt], 0, 0, 0);
      acc[1][nt] = __builtin_amdgcn_mfma_f32_16x16x32_bf16(a1, b, acc[1][nt], 0, 0, 0);
    }
  }
  __syncthreads();
  unsigned short* lT = smem;   // transposed tile [c 128][r 136]
#pragma unroll
  for (int mt = 0; mt < 2; ++mt)
#pragma unroll
    for (int nt = 0; nt < 8; ++nt)
#pragma unroll
      for (int i = 0; i < 4; ++i) {
        int r = w * 32 + mt * 16 + q * 4 + i;
        lT[(nt * 16 + l15) * 136 + r] = f2bf(dinv[r0 + r] * acc[mt][nt][i]);
      }
  __syncthreads();
#pragma unroll
  for (int cc = 0; cc < 8; ++cc) {
    int ch = t + cc * 256;
    int c = ch >> 4, c16 = ch & 15;
    *(bf16x8*)&ZT[(size_t)c * ldz + r0 + c16 * 8] = *(const bf16x8*)&lT[c * 136 + c16 * 8];
  }
}

// ---------------- driver ----------------

extern "C" void kernel_launch(void* const* d_in, const int* in_sizes, int n_in,
                              void* d_out, int out_size, void* d_ws, size_t ws_size,
                              hipStream_t stream) {
  (void)in_sizes; (void)n_in; (void)out_size;
  const float* X   = (const float*)d_in[0];
  const float* A   = (const float*)d_in[1];
  const float* Wup = (const float*)d_in[2];
  const float* bup = (const float*)d_in[3];
  const float* W1  = (const float*)d_in[4];
  const float* b1  = (const float*)d_in[5];
  const float* W2  = (const float*)d_in[6];
  const float* b2  = (const float*)d_in[7];

  const size_t ADJ_BYTES = (size_t)M_NODES * M_NODES * 2;
  char* ws = (char*)d_ws;
  size_t off = 0;
  auto alloc = [&](size_t bytes) {
    char* p = ws + off;
    off += (bytes + 255) & ~(size_t)255;
    return p;
  };
  float*          accb    = (float*)alloc((size_t)SPLITS * M_NODES * DIM * 4);  // 33.5 MB
  unsigned short* Xu      = (unsigned short*)alloc((size_t)M_NODES * DIM * 2);
  unsigned short* ZT      = (unsigned short*)alloc((size_t)DIM * M_NODES * 2);
  unsigned short* XT      = (unsigned short*)alloc((size_t)DIM * N_NODES * 2);
  unsigned short* W1T     = (unsigned short*)alloc(DIM * DIM * 2);
  unsigned short* W2T     = (unsigned short*)alloc(DIM * DIM * 2);
  float*          colsumA = (float*)alloc(N_NODES * 4);
  float*          deg     = (float*)alloc(M_NODES * 4);
  float*          dinv    = (float*)alloc(M_NODES * 4);

  unsigned short* Adj;
  if (ws_size >= off + ADJ_BYTES) Adj = (unsigned short*)(ws + off);
  else                            Adj = (unsigned short*)d_out;  // Adj is dead before final write
  unsigned short* Wupb = Adj;   // W_up bf16 (32MB) aliases Adj space, consumed before Adj is filled

  unsigned short* XuNew = Xu + (size_t)N_NODES * DIM;

  hipMemsetAsync(colsumA, 0, N_NODES * 4, stream);
  cast_x_kernel<<<N_NODES * DIM / 256, 256, 0, stream>>>(X, Xu, XT);
  cast_wup_kernel<<<(N_NODES * (size_t)N_NODES / 4) / 256, 256, 0, stream>>>(
      (const float4*)Wup, (ushort4*)Wupb);
  cast_wt_kernel<<<64, 256, 0, stream>>>(W1, W1T);
  cast_wt_kernel<<<64, 256, 0, stream>>>(W2, W2T);

  // new = W_up @ X (+ b_up per-row)
  gemm_split_kernel<<<dim3(N_NODES / 128, SPLITS), 256, 0, stream>>>(
      Wupb, N_NODES, XT, N_NODES, accb, N_NODES, N_NODES / SPLITS);
  reduce_acc_kernel<<<N_NODES * DIM / 256, 256, 0, stream>>>(
      accb, N_NODES, XuNew, bup, nullptr, nullptr, 0);

  // initial Adj blocks + deg
  cast_a_kernel<<<dim3(N_NODES / 256, N_NODES / 128), 256, 0, stream>>>(A, Adj, colsumA);
  init_deg_kernel<<<M_NODES / 256, 256, 0, stream>>>(colsumA, deg);
  rebuild_kernel<0><<<dim3(N_NODES / 128, N_NODES / 128), 256, 0, stream>>>(
      XuNew, XuNew, Adj + (size_t)N_NODES * M_NODES + N_NODES, M_NODES, deg + N_NODES);
  dinv_kernel<<<M_NODES / 256, 256, 0, stream>>>(deg, dinv);

  for (int it = 0; it < 3; ++it) {
    // conv1
    yz_kernel<<<M_NODES / 128, 256, 0, stream>>>(Xu, W1T, dinv, ZT, M_NODES);
    gemm_split_kernel<<<dim3(M_NODES / 128, SPLITS), 256, 0, stream>>>(
        Adj, M_NODES, ZT, M_NODES, accb, M_NODES, M_NODES / SPLITS);
    reduce_acc_kernel<<<M_NODES * DIM / 256, 256, 0, stream>>>(
        accb, M_NODES, Xu, nullptr, b1, dinv, 1);
    // mid-loop Adj rebuild + deg
    hipMemsetAsync(deg, 0, M_NODES * 4, stream);
    rebuild_kernel<0><<<dim3(M_NODES / 128, M_NODES / 128), 256, 0, stream>>>(
        Xu, Xu, Adj, M_NODES, deg);
    dinv_kernel<<<M_NODES / 256, 256, 0, stream>>>(deg, dinv);
    // conv2
    yz_kernel<<<M_NODES / 128, 256, 0, stream>>>(Xu, W2T, dinv, ZT, M_NODES);
    gemm_split_kernel<<<dim3(M_NODES / 128, SPLITS), 256, 0, stream>>>(
        Adj, M_NODES, ZT, M_NODES, accb, M_NODES, M_NODES / SPLITS);
    reduce_acc_kernel<<<M_NODES * DIM / 256, 256, 0, stream>>>(
        accb, M_NODES, Xu, nullptr, b2, dinv, 1);
    // A_out only matters on the last iteration (dead code otherwise)
    if (it == 2)
      rebuild_kernel<1><<<dim3(M_NODES / 128, M_NODES / 128), 256, 0, stream>>>(
          Xu, Xu, d_out, M_NODES, nullptr);
  }
}